// Round 1
// baseline (822.195 us; speedup 1.0000x reference)
//
#include <hip/hip_runtime.h>
#include <hip/hip_fp16.h>

typedef _Float16 f16x8 __attribute__((ext_vector_type(8)));
typedef float f32x4 __attribute__((ext_vector_type(4)));

// Problem: B=2, L=2048, C=R=64. heads h = b*16 + mc*4 + mr (32 total),
// feature f = hc*16 + hr (256). Workspace (f16):
//   Q [32][2048][256], K [32][2048][256], Vt [32][256][2048], O [32][2048][256]

// ---------------- Kernel A: QKV bilinear projection + qkv-split scatter ---------
__global__ __launch_bounds__(256) void qkv_kernel(
    const float* __restrict__ x, const float* __restrict__ u,
    const float* __restrict__ v, _Float16* __restrict__ Q,
    _Float16* __restrict__ K, _Float16* __restrict__ Vt) {
  __shared__ float xs[4096];    // x[b,l] as [n][d]
  __shared__ float us[4096];    // qkv_u as [n][m]
  __shared__ float tmps[4096];  // tmp transposed: [d][m]
  const int bl = blockIdx.x;
  const int b = bl >> 11, l = bl & 2047;
  const int t = threadIdx.x;
  {
    const float4* xg = (const float4*)(x + ((size_t)bl << 12));
    const float4* ug = (const float4*)u;
#pragma unroll
    for (int i = 0; i < 4; ++i) {
      ((float4*)xs)[t + 256 * i] = xg[t + 256 * i];
      ((float4*)us)[t + 256 * i] = ug[t + 256 * i];
    }
  }
  __syncthreads();
  // tmp[m][d] = sum_n u[n][m] * x[n][d]; each thread a 4x4 tile
  {
    const int m0 = (t >> 4) << 2, d0 = (t & 15) << 2;
    float acc[4][4] = {};
    for (int n = 0; n < 64; ++n) {
      float uv[4], xv[4];
      *(float4*)uv = *(const float4*)&us[n * 64 + m0];
      *(float4*)xv = *(const float4*)&xs[n * 64 + d0];
#pragma unroll
      for (int i = 0; i < 4; ++i)
#pragma unroll
        for (int j = 0; j < 4; ++j) acc[i][j] += uv[i] * xv[j];
    }
#pragma unroll
    for (int i = 0; i < 4; ++i)
#pragma unroll
      for (int j = 0; j < 4; ++j) tmps[(d0 + j) * 64 + m0 + i] = acc[i][j];
  }
  __syncthreads();
  // qkv[m][k] = sum_d tmp[m][d] * v[d][k]; each thread 4m x 12k, then scatter
  {
    const int m0 = (t >> 4) << 2, k0 = (t & 15) * 12;
    float acc[4][12] = {};
    for (int d = 0; d < 64; ++d) {
      float tv[4], vv[12];
      *(float4*)tv = *(const float4*)&tmps[d * 64 + m0];
      const float* vr = v + d * 192 + k0;
      *(float4*)&vv[0] = *(const float4*)&vr[0];
      *(float4*)&vv[4] = *(const float4*)&vr[4];
      *(float4*)&vv[8] = *(const float4*)&vr[8];
#pragma unroll
      for (int i = 0; i < 4; ++i)
#pragma unroll
        for (int j = 0; j < 12; ++j) acc[i][j] += tv[i] * vv[j];
    }
#pragma unroll
    for (int i = 0; i < 4; ++i)
#pragma unroll
      for (int j = 0; j < 12; ++j) {
        const int idx = (m0 + i) * 192 + k0 + j;  // flat (m,k) index
        const int t3 = idx >> 12;                 // q/k/v selector
        const int ch = (idx >> 6) & 63;           // mc*16 + hc
        const int rl = idx & 63;                  // mr*16 + hr
        const int f = ((ch & 15) << 4) | (rl & 15);
        const int h = (b << 4) | (((ch >> 4)) << 2) | (rl >> 4);
        const _Float16 val = (_Float16)acc[i][j];
        if (t3 == 0)
          Q[(((size_t)h * 2048 + l) << 8) + f] = val;
        else if (t3 == 1)
          K[(((size_t)h * 2048 + l) << 8) + f] = val;
        else
          Vt[(((size_t)(h << 8) + f) << 11) + l] = val;
      }
  }
}

// ---------------- Kernel B: flash attention, MFMA 16x16x32 f16 ------------------
__global__ __launch_bounds__(256) void attn_kernel(
    const _Float16* __restrict__ Q, const _Float16* __restrict__ K,
    const _Float16* __restrict__ Vt, _Float16* __restrict__ O) {
  constexpr int KS = 264;  // K tile row stride (f16): 256 + 8 pad
  constexpr int VS = 40;   // V tile row stride (f16): 32 + 8 pad
  __shared__ _Float16 Ks[32 * KS];      // [key(32)][feat(256)]
  __shared__ _Float16 Vs[256 * VS];     // [feat(256)][key(32)]
  __shared__ _Float16 Ps[4][16 * 32];   // per-wave P transpose buffer
  const int h = blockIdx.x >> 5;
  const int qt = blockIdx.x & 31;
  const int tid = threadIdx.x;
  const int w = tid >> 6, lane = tid & 63;
  const int l15 = lane & 15, quad = lane >> 4;
  const int q0 = qt * 64 + w * 16;  // this wave's 16 queries

  // Q fragments (A-operand: m=lane&15 -> query, k=quad*8+j -> feature)
  f16x8 qf[8];
  const _Float16* qbase = Q + (((size_t)h * 2048 + q0 + l15) << 8) + quad * 8;
#pragma unroll
  for (int kc = 0; kc < 8; ++kc) qf[kc] = *(const f16x8*)(qbase + kc * 32);

  f32x4 oacc[16];
#pragma unroll
  for (int ch = 0; ch < 16; ++ch) oacc[ch] = (f32x4){0.f, 0.f, 0.f, 0.f};
  float m2[4] = {-1e30f, -1e30f, -1e30f, -1e30f};  // running max (base-2 units)
  float ell[4] = {0.f, 0.f, 0.f, 0.f};
  const float SC = 23.083120654223414f;  // 16 * log2(e): ref divides by SCALE=1/16

  for (int kt = 0; kt < 64; ++kt) {
    const int k0 = kt * 32;
    __syncthreads();
    {  // stage K tile: 32 rows x 256 feats
      const int row = tid >> 3, seg = (tid & 7) * 32;
      const _Float16* src = K + (((size_t)h * 2048 + k0 + row) << 8) + seg;
      _Float16* dst = Ks + row * KS + seg;
#pragma unroll
      for (int o = 0; o < 4; ++o)
        *(f16x8*)(dst + o * 8) = *(const f16x8*)(src + o * 8);
    }
    {  // stage V tile (transposed layout): 256 feats x 32 keys
      const _Float16* src = Vt + (((size_t)(h << 8) + tid) << 11) + k0;
      _Float16* dst = Vs + tid * VS;
#pragma unroll
      for (int o = 0; o < 4; ++o)
        *(f16x8*)(dst + o * 8) = *(const f16x8*)(src + o * 8);
    }
    __syncthreads();
    // S = Q K^T over 32 keys (two 16-key halves)
    f32x4 c0 = {0.f, 0.f, 0.f, 0.f}, c1 = {0.f, 0.f, 0.f, 0.f};
#pragma unroll
    for (int kc = 0; kc < 8; ++kc) {
      f16x8 kf0 = *(const f16x8*)(Ks + l15 * KS + kc * 32 + quad * 8);
      f16x8 kf1 = *(const f16x8*)(Ks + (16 + l15) * KS + kc * 32 + quad * 8);
      c0 = __builtin_amdgcn_mfma_f32_16x16x32_f16(qf[kc], kf0, c0, 0, 0, 0);
      c1 = __builtin_amdgcn_mfma_f32_16x16x32_f16(qf[kc], kf1, c1, 0, 0, 0);
    }
    // online softmax; C/D layout: row (query) = quad*4+r, col (key) = l15
    float p0[4], p1[4], alpha[4];
#pragma unroll
    for (int r = 0; r < 4; ++r) {
      float s0 = c0[r] * SC, s1 = c1[r] * SC;
      float mx = fmaxf(s0, s1);
      mx = fmaxf(mx, __shfl_xor(mx, 1));
      mx = fmaxf(mx, __shfl_xor(mx, 2));
      mx = fmaxf(mx, __shfl_xor(mx, 4));
      mx = fmaxf(mx, __shfl_xor(mx, 8));
      float mn = fmaxf(m2[r], mx);
      alpha[r] = exp2f(m2[r] - mn);
      m2[r] = mn;
      p0[r] = exp2f(s0 - mn);
      p1[r] = exp2f(s1 - mn);
      float rs = p0[r] + p1[r];
      rs += __shfl_xor(rs, 1);
      rs += __shfl_xor(rs, 2);
      rs += __shfl_xor(rs, 4);
      rs += __shfl_xor(rs, 8);
      ell[r] = ell[r] * alpha[r] + rs;
    }
    f32x4 av = {alpha[0], alpha[1], alpha[2], alpha[3]};
#pragma unroll
    for (int ch = 0; ch < 16; ++ch) oacc[ch] *= av;
    // P: C-layout -> LDS -> A-layout
    _Float16* pb = Ps[w];
#pragma unroll
    for (int r = 0; r < 4; ++r) {
      pb[(quad * 4 + r) * 32 + l15] = (_Float16)p0[r];
      pb[(quad * 4 + r) * 32 + 16 + l15] = (_Float16)p1[r];
    }
    asm volatile("s_waitcnt lgkmcnt(0)" ::: "memory");
    f16x8 pf = *(const f16x8*)(pb + l15 * 32 + quad * 8);
    // O += P V  (B-operand: n=l15 -> feat, k=quad*8+j -> key)
#pragma unroll
    for (int ch = 0; ch < 16; ++ch) {
      f16x8 vf = *(const f16x8*)(Vs + (ch * 16 + l15) * VS + quad * 8);
      oacc[ch] = __builtin_amdgcn_mfma_f32_16x16x32_f16(pf, vf, oacc[ch], 0, 0, 0);
    }
  }
  // epilogue: O /= l, write [h][l][f]
  float inv[4];
#pragma unroll
  for (int r = 0; r < 4; ++r) inv[r] = 1.f / ell[r];
  _Float16* ob = O + (((size_t)h * 2048 + q0 + quad * 4) << 8) + l15;
#pragma unroll
  for (int r = 0; r < 4; ++r)
#pragma unroll
    for (int ch = 0; ch < 16; ++ch)
      ob[((size_t)r << 8) + ch * 16] = (_Float16)(oacc[ch][r] * inv[r]);
}

// ---------------- Kernel C: gather heads + output bilinear projection -----------
__global__ __launch_bounds__(256) void proj_kernel(
    const _Float16* __restrict__ O, const float* __restrict__ pu,
    const float* __restrict__ pv, float* __restrict__ out) {
  __shared__ float os[4096];    // [n=mc*16+hc][d=mr*16+hr]
  __shared__ float pus[4096];   // proj_u [n][m]
  __shared__ float tmps[4096];  // [d][m]
  const int bl = blockIdx.x;
  const int b = bl >> 11, l = bl & 2047;
  const int t = threadIdx.x;
#pragma unroll
  for (int i = 0; i < 4; ++i)
    ((float4*)pus)[t + 256 * i] = ((const float4*)pu)[t + 256 * i];
  {  // gather this (b,l)'s 64x64 attention output from the 16 heads
    const int hh = t >> 4, hc = t & 15;
    const int mc = hh >> 2, mr = hh & 3;
    const int hg = (b << 4) | hh;
    const _Float16* src = O + (((size_t)hg * 2048 + l) << 8) + hc * 16;
    float* dst = os + (mc * 16 + hc) * 64 + mr * 16;
    f16x8 v0 = *(const f16x8*)(src);
    f16x8 v1 = *(const f16x8*)(src + 8);
#pragma unroll
    for (int j = 0; j < 8; ++j) {
      dst[j] = (float)v0[j];
      dst[8 + j] = (float)v1[j];
    }
  }
  __syncthreads();
  {  // tmp[m][d] = sum_n pu[n][m] * os[n][d]
    const int m0 = (t >> 4) << 2, d0 = (t & 15) << 2;
    float acc[4][4] = {};
    for (int n = 0; n < 64; ++n) {
      float uv[4], xv[4];
      *(float4*)uv = *(const float4*)&pus[n * 64 + m0];
      *(float4*)xv = *(const float4*)&os[n * 64 + d0];
#pragma unroll
      for (int i = 0; i < 4; ++i)
#pragma unroll
        for (int j = 0; j < 4; ++j) acc[i][j] += uv[i] * xv[j];
    }
#pragma unroll
    for (int i = 0; i < 4; ++i)
#pragma unroll
      for (int j = 0; j < 4; ++j) tmps[(d0 + j) * 64 + m0 + i] = acc[i][j];
  }
  __syncthreads();
  {  // out[m][k] = sum_d tmp[m][d] * pv[d][k]
    const int m0 = (t >> 4) << 2, k0 = (t & 15) << 2;
    float acc[4][4] = {};
    for (int d = 0; d < 64; ++d) {
      float tv[4], vv[4];
      *(float4*)tv = *(const float4*)&tmps[d * 64 + m0];
      *(float4*)vv = *(const float4*)&pv[d * 64 + k0];
#pragma unroll
      for (int i = 0; i < 4; ++i)
#pragma unroll
        for (int j = 0; j < 4; ++j) acc[i][j] += tv[i] * vv[j];
    }
    float* og = out + ((size_t)bl << 12);
#pragma unroll
    for (int i = 0; i < 4; ++i) {
      float4 r;
      r.x = acc[i][0]; r.y = acc[i][1]; r.z = acc[i][2]; r.w = acc[i][3];
      *(float4*)&og[(m0 + i) * 64 + k0] = r;
    }
  }
}

extern "C" void kernel_launch(void* const* d_in, const int* in_sizes, int n_in,
                              void* d_out, int out_size, void* d_ws, size_t ws_size,
                              hipStream_t stream) {
  (void)in_sizes; (void)n_in; (void)out_size; (void)ws_size;
  const float* x = (const float*)d_in[0];
  const float* u = (const float*)d_in[1];
  const float* v = (const float*)d_in[2];
  const float* pu = (const float*)d_in[3];
  const float* pv = (const float*)d_in[4];
  const size_t SEG = (size_t)32 * 2048 * 256;  // 16.7M f16 elements
  _Float16* Q = (_Float16*)d_ws;
  _Float16* K = Q + SEG;
  _Float16* Vt = K + SEG;
  _Float16* O = Vt + SEG;
  qkv_kernel<<<4096, 256, 0, stream>>>(x, u, v, Q, K, Vt);
  attn_kernel<<<1024, 256, 0, stream>>>(Q, K, Vt, O);
  proj_kernel<<<4096, 256, 0, stream>>>(O, pu, pv, (float*)d_out);
}

// Round 2
// 802.660 us; speedup vs baseline: 1.0243x; 1.0243x over previous
//
#include <hip/hip_runtime.h>
#include <hip/hip_fp16.h>

typedef _Float16 f16x8 __attribute__((ext_vector_type(8)));
typedef float f32x4 __attribute__((ext_vector_type(4)));

// Problem: B=2, L=2048, C=R=64. heads h = b*16 + mc*4 + mr (32 total),
// feature f = hc*16 + hr (256). Workspace (f16):
//   Q [32][2048][256], K [32][2048][256], Vt [32][256][2048], O [32][2048][256]

__device__ __forceinline__ void stage16(const _Float16* g, _Float16* l) {
#if __has_builtin(__builtin_amdgcn_global_load_lds)
  __builtin_amdgcn_global_load_lds(
      (const __attribute__((address_space(1))) void*)g,
      (__attribute__((address_space(3))) void*)l, 16, 0, 0);
#else
  *(f16x8*)l = *(const f16x8*)g;
#endif
}

// ---------------- Kernel A: QKV bilinear projection + qkv-split scatter ---------
__global__ __launch_bounds__(256) void qkv_kernel(
    const float* __restrict__ x, const float* __restrict__ u,
    const float* __restrict__ v, _Float16* __restrict__ Q,
    _Float16* __restrict__ K, _Float16* __restrict__ Vt) {
  __shared__ float xs[4096];    // x[b,l] as [n][d]
  __shared__ float us[4096];    // qkv_u as [n][m]
  __shared__ float tmps[4096];  // tmp transposed: [d][m]
  const int bl = blockIdx.x;
  const int b = bl >> 11, l = bl & 2047;
  const int t = threadIdx.x;
  {
    const float4* xg = (const float4*)(x + ((size_t)bl << 12));
    const float4* ug = (const float4*)u;
#pragma unroll
    for (int i = 0; i < 4; ++i) {
      ((float4*)xs)[t + 256 * i] = xg[t + 256 * i];
      ((float4*)us)[t + 256 * i] = ug[t + 256 * i];
    }
  }
  __syncthreads();
  // tmp[m][d] = sum_n u[n][m] * x[n][d]; each thread a 4x4 tile
  {
    const int m0 = (t >> 4) << 2, d0 = (t & 15) << 2;
    float acc[4][4] = {};
    for (int n = 0; n < 64; ++n) {
      float uv[4], xv[4];
      *(float4*)uv = *(const float4*)&us[n * 64 + m0];
      *(float4*)xv = *(const float4*)&xs[n * 64 + d0];
#pragma unroll
      for (int i = 0; i < 4; ++i)
#pragma unroll
        for (int j = 0; j < 4; ++j) acc[i][j] += uv[i] * xv[j];
    }
#pragma unroll
    for (int i = 0; i < 4; ++i)
#pragma unroll
      for (int j = 0; j < 4; ++j) tmps[(d0 + j) * 64 + m0 + i] = acc[i][j];
  }
  __syncthreads();
  // qkv[m][k] = sum_d tmp[m][d] * v[d][k]; each thread 4m x 12k, then scatter
  {
    const int m0 = (t >> 4) << 2, k0 = (t & 15) * 12;
    float acc[4][12] = {};
    for (int d = 0; d < 64; ++d) {
      float tv[4], vv[12];
      *(float4*)tv = *(const float4*)&tmps[d * 64 + m0];
      const float* vr = v + d * 192 + k0;
      *(float4*)&vv[0] = *(const float4*)&vr[0];
      *(float4*)&vv[4] = *(const float4*)&vr[4];
      *(float4*)&vv[8] = *(const float4*)&vr[8];
#pragma unroll
      for (int i = 0; i < 4; ++i)
#pragma unroll
        for (int j = 0; j < 12; ++j) acc[i][j] += tv[i] * vv[j];
    }
#pragma unroll
    for (int i = 0; i < 4; ++i)
#pragma unroll
      for (int j = 0; j < 12; ++j) {
        const int idx = (m0 + i) * 192 + k0 + j;  // flat (m,k) index
        const int t3 = idx >> 12;                 // q/k/v selector
        const int ch = (idx >> 6) & 63;           // mc*16 + hc
        const int rl = idx & 63;                  // mr*16 + hr
        const int f = ((ch & 15) << 4) | (rl & 15);
        const int h = (b << 4) | (((ch >> 4)) << 2) | (rl >> 4);
        const _Float16 val = (_Float16)acc[i][j];
        if (t3 == 0)
          Q[(((size_t)h * 2048 + l) << 8) + f] = val;
        else if (t3 == 1)
          K[(((size_t)h * 2048 + l) << 8) + f] = val;
        else
          Vt[(((size_t)(h << 8) + f) << 11) + l] = val;
      }
  }
}

// ---------------- Kernel B: flash attention, 32 queries/wave, MFMA 16x16x32 -----
// LDS: Ks (unpadded, XOR-swizzled 16B units), Vs [feat][key] unpadded, Ps per-wave.
__global__ __launch_bounds__(256, 2) void attn_kernel(
    const _Float16* __restrict__ Q, const _Float16* __restrict__ K,
    const _Float16* __restrict__ Vt, _Float16* __restrict__ O) {
  __shared__ _Float16 Ks[32 * 256];   // mem[row][u] = K[row][u ^ (row&7)] (16B units)
  __shared__ _Float16 Vs[256 * 32];   // [feat][key]
  __shared__ _Float16 Ps[4][32 * 32]; // per-wave P transpose buffer [q][key]
  const int h = blockIdx.x >> 4;      // 32 heads
  const int qt = blockIdx.x & 15;     // 16 q-tiles of 128
  const int tid = threadIdx.x;
  const int w = tid >> 6, lane = tid & 63;
  const int l15 = lane & 15, quad = lane >> 4;
  const int q0 = qt * 128 + w * 32;   // this wave's 32 queries

  // Q fragments, two 16-query halves (A-op: m=l15 -> query, k=quad*8+j -> feat)
  f16x8 qf[2][8];
#pragma unroll
  for (int qh = 0; qh < 2; ++qh) {
    const _Float16* qb = Q + (((size_t)h * 2048 + q0 + qh * 16 + l15) << 8) + quad * 8;
#pragma unroll
    for (int kc = 0; kc < 8; ++kc) qf[qh][kc] = *(const f16x8*)(qb + kc * 32);
  }

  f32x4 oacc[2][16];
#pragma unroll
  for (int qh = 0; qh < 2; ++qh)
#pragma unroll
    for (int ch = 0; ch < 16; ++ch) oacc[qh][ch] = (f32x4){0.f, 0.f, 0.f, 0.f};
  float m2[2][4], ell[2][4];
#pragma unroll
  for (int qh = 0; qh < 2; ++qh)
#pragma unroll
    for (int r = 0; r < 4; ++r) { m2[qh][r] = -1e30f; ell[qh][r] = 0.f; }
  const float SC = 23.083120654223414f;  // 16 * log2(e)

  const _Float16* Kt = K + (((size_t)h * 2048) << 8);
  const _Float16* Vtb = Vt + (((size_t)h << 8) << 11);
  // per-thread staging chunk geometry (4 K chunks + 4 V chunks of 16B)
  const int krow[4] = {(tid) >> 5, (tid + 256) >> 5, (tid + 512) >> 5, (tid + 768) >> 5};

  for (int kt = 0; kt < 64; ++kt) {
    const int k0 = kt * 32;
    __syncthreads();  // previous tile fully consumed
#pragma unroll
    for (int o = 0; o < 4; ++o) {
      const int c = tid + o * 256;
      const int row = krow[o], unit = c & 31;
      // K: global source swizzled, LDS flat (wave-uniform base + lane*16)
      stage16(Kt + (((size_t)(k0 + row)) << 8) + (((unit ^ (row & 7))) << 3),
              Ks + c * 8);
      // V: [feat][key] flat
      const int f = c >> 2, ku = c & 3;
      stage16(Vtb + (((size_t)f) << 11) + k0 + ku * 8, Vs + c * 8);
    }
    asm volatile("s_waitcnt vmcnt(0)" ::: "memory");
    __syncthreads();  // all staging visible

    // S = Q K^T : two key-halves, two query-halves; K frags shared across qh
    f32x4 c00 = {0.f,0.f,0.f,0.f}, c01 = c00, c10 = c00, c11 = c00;
#pragma unroll
    for (int kc = 0; kc < 8; ++kc) {
      const int u0 = ((kc * 4 + quad) ^ (l15 & 7)) << 3;  // swizzled 16B unit -> halves
      f16x8 kf0 = *(const f16x8*)(Ks + l15 * 256 + u0);
      f16x8 kf1 = *(const f16x8*)(Ks + (16 + l15) * 256 + u0);
      c00 = __builtin_amdgcn_mfma_f32_16x16x32_f16(qf[0][kc], kf0, c00, 0, 0, 0);
      c01 = __builtin_amdgcn_mfma_f32_16x16x32_f16(qf[0][kc], kf1, c01, 0, 0, 0);
      c10 = __builtin_amdgcn_mfma_f32_16x16x32_f16(qf[1][kc], kf0, c10, 0, 0, 0);
      c11 = __builtin_amdgcn_mfma_f32_16x16x32_f16(qf[1][kc], kf1, c11, 0, 0, 0);
    }

    // online softmax (lane-partial ell; reduce only max per iter)
    float alpha[2][4];
    bool upd = false;
    _Float16* pb = Ps[w];
#pragma unroll
    for (int qh = 0; qh < 2; ++qh) {
#pragma unroll
      for (int r = 0; r < 4; ++r) {
        const float s0 = (qh ? c10[r] : c00[r]) * SC;
        const float s1 = (qh ? c11[r] : c01[r]) * SC;
        float mx = fmaxf(s0, s1);
        mx = fmaxf(mx, __shfl_xor(mx, 1));
        mx = fmaxf(mx, __shfl_xor(mx, 2));
        mx = fmaxf(mx, __shfl_xor(mx, 4));
        mx = fmaxf(mx, __shfl_xor(mx, 8));
        const float mo = m2[qh][r];
        const float mn = fmaxf(mo, mx);
        m2[qh][r] = mn;
        upd |= (mx > mo);
        const float a = exp2f(mo - mn);
        alpha[qh][r] = a;
        const float p0 = exp2f(s0 - mn), p1 = exp2f(s1 - mn);
        ell[qh][r] = ell[qh][r] * a + (p0 + p1);
        const int rowq = (qh * 16 + quad * 4 + r) * 32;
        pb[rowq + l15] = (_Float16)p0;
        pb[rowq + 16 + l15] = (_Float16)p1;
      }
    }
    if (__any(upd)) {
#pragma unroll
      for (int qh = 0; qh < 2; ++qh) {
        const f32x4 av = {alpha[qh][0], alpha[qh][1], alpha[qh][2], alpha[qh][3]};
#pragma unroll
        for (int ch = 0; ch < 16; ++ch) oacc[qh][ch] *= av;
      }
    }
    asm volatile("s_waitcnt lgkmcnt(0)" ::: "memory");
    f16x8 pf0 = *(const f16x8*)(pb + l15 * 32 + quad * 8);
    f16x8 pf1 = *(const f16x8*)(pb + (16 + l15) * 32 + quad * 8);
    // O += P V  (V frags shared across the two query-halves)
#pragma unroll
    for (int ch = 0; ch < 16; ++ch) {
      f16x8 vf = *(const f16x8*)(Vs + (ch * 16 + l15) * 32 + quad * 8);
      oacc[0][ch] = __builtin_amdgcn_mfma_f32_16x16x32_f16(pf0, vf, oacc[0][ch], 0, 0, 0);
      oacc[1][ch] = __builtin_amdgcn_mfma_f32_16x16x32_f16(pf1, vf, oacc[1][ch], 0, 0, 0);
    }
  }

  // epilogue: reduce lane-partial ell across the 16-lane row groups, write O
#pragma unroll
  for (int qh = 0; qh < 2; ++qh) {
    float inv[4];
#pragma unroll
    for (int r = 0; r < 4; ++r) {
      float e = ell[qh][r];
      e += __shfl_xor(e, 1);
      e += __shfl_xor(e, 2);
      e += __shfl_xor(e, 4);
      e += __shfl_xor(e, 8);
      inv[r] = 1.f / e;
    }
    _Float16* ob = O + (((size_t)h * 2048 + q0 + qh * 16 + quad * 4) << 8) + l15;
#pragma unroll
    for (int r = 0; r < 4; ++r)
#pragma unroll
      for (int ch = 0; ch < 16; ++ch)
        ob[((size_t)r << 8) + ch * 16] = (_Float16)(oacc[qh][ch][r] * inv[r]);
  }
}

// ---------------- Kernel C: gather heads + output bilinear projection -----------
__global__ __launch_bounds__(256) void proj_kernel(
    const _Float16* __restrict__ O, const float* __restrict__ pu,
    const float* __restrict__ pv, float* __restrict__ out) {
  __shared__ float os[4096];    // [n=mc*16+hc][d=mr*16+hr]
  __shared__ float pus[4096];   // proj_u [n][m]
  __shared__ float tmps[4096];  // [d][m]
  const int bl = blockIdx.x;
  const int b = bl >> 11, l = bl & 2047;
  const int t = threadIdx.x;
#pragma unroll
  for (int i = 0; i < 4; ++i)
    ((float4*)pus)[t + 256 * i] = ((const float4*)pu)[t + 256 * i];
  {  // gather this (b,l)'s 64x64 attention output from the 16 heads
    const int hh = t >> 4, hc = t & 15;
    const int mc = hh >> 2, mr = hh & 3;
    const int hg = (b << 4) | hh;
    const _Float16* src = O + (((size_t)hg * 2048 + l) << 8) + hc * 16;
    float* dst = os + (mc * 16 + hc) * 64 + mr * 16;
    f16x8 v0 = *(const f16x8*)(src);
    f16x8 v1 = *(const f16x8*)(src + 8);
#pragma unroll
    for (int j = 0; j < 8; ++j) {
      dst[j] = (float)v0[j];
      dst[8 + j] = (float)v1[j];
    }
  }
  __syncthreads();
  {  // tmp[m][d] = sum_n pu[n][m] * os[n][d]
    const int m0 = (t >> 4) << 2, d0 = (t & 15) << 2;
    float acc[4][4] = {};
    for (int n = 0; n < 64; ++n) {
      float uv[4], xv[4];
      *(float4*)uv = *(const float4*)&pus[n * 64 + m0];
      *(float4*)xv = *(const float4*)&os[n * 64 + d0];
#pragma unroll
      for (int i = 0; i < 4; ++i)
#pragma unroll
        for (int j = 0; j < 4; ++j) acc[i][j] += uv[i] * xv[j];
    }
#pragma unroll
    for (int i = 0; i < 4; ++i)
#pragma unroll
      for (int j = 0; j < 4; ++j) tmps[(d0 + j) * 64 + m0 + i] = acc[i][j];
  }
  __syncthreads();
  {  // out[m][k] = sum_d tmp[m][d] * pv[d][k]
    const int m0 = (t >> 4) << 2, k0 = (t & 15) << 2;
    float acc[4][4] = {};
    for (int d = 0; d < 64; ++d) {
      float tv[4], vv[4];
      *(float4*)tv = *(const float4*)&tmps[d * 64 + m0];
      *(float4*)vv = *(const float4*)&pv[d * 64 + k0];
#pragma unroll
      for (int i = 0; i < 4; ++i)
#pragma unroll
        for (int j = 0; j < 4; ++j) acc[i][j] += tv[i] * vv[j];
    }
    float* og = out + ((size_t)bl << 12);
#pragma unroll
    for (int i = 0; i < 4; ++i) {
      float4 r;
      r.x = acc[i][0]; r.y = acc[i][1]; r.z = acc[i][2]; r.w = acc[i][3];
      *(float4*)&og[(m0 + i) * 64 + k0] = r;
    }
  }
}

extern "C" void kernel_launch(void* const* d_in, const int* in_sizes, int n_in,
                              void* d_out, int out_size, void* d_ws, size_t ws_size,
                              hipStream_t stream) {
  (void)in_sizes; (void)n_in; (void)out_size; (void)ws_size;
  const float* x = (const float*)d_in[0];
  const float* u = (const float*)d_in[1];
  const float* v = (const float*)d_in[2];
  const float* pu = (const float*)d_in[3];
  const float* pv = (const float*)d_in[4];
  const size_t SEG = (size_t)32 * 2048 * 256;  // 16.7M f16 elements
  _Float16* Q = (_Float16*)d_ws;
  _Float16* K = Q + SEG;
  _Float16* Vt = K + SEG;
  _Float16* O = Vt + SEG;
  qkv_kernel<<<4096, 256, 0, stream>>>(x, u, v, Q, K, Vt);
  attn_kernel<<<512, 256, 0, stream>>>(Q, K, Vt, O);
  proj_kernel<<<4096, 256, 0, stream>>>(O, pu, pv, (float*)d_out);
}

// Round 3
// 694.291 us; speedup vs baseline: 1.1842x; 1.1561x over previous
//
#include <hip/hip_runtime.h>
#include <hip/hip_fp16.h>

typedef _Float16 f16x8 __attribute__((ext_vector_type(8)));
typedef float f32x4 __attribute__((ext_vector_type(4)));

// Problem: B=2, L=2048, C=R=64. heads h = b*16 + mc*4 + mr (32 total),
// feature f = hc*16 + hr (256). Workspace (f16):
//   Q [32][2048][256], K [32][2048][256], Vt [32][256][2048], O/V [32][2048][256]
//   (V aliases O: V is consumed by vtrans before attn writes O)

__device__ __forceinline__ void stage16(const _Float16* g, _Float16* l) {
  __builtin_amdgcn_global_load_lds(
      (const __attribute__((address_space(1))) void*)g,
      (__attribute__((address_space(3))) void*)l, 16, 0, 0);
}

// ---------------- Kernel A: QKV bilinear projection + qkv-split scatter ---------
__global__ __launch_bounds__(256) void qkv_kernel(
    const float* __restrict__ x, const float* __restrict__ u,
    const float* __restrict__ v, _Float16* __restrict__ Q,
    _Float16* __restrict__ K, _Float16* __restrict__ V) {
  __shared__ float xs[4096];    // x[b,l] as [n][d]
  __shared__ float us[4096];    // qkv_u as [n][m]
  __shared__ float tmps[4096];  // tmp transposed: [d][m]
  const int bl = blockIdx.x;
  const int b = bl >> 11, l = bl & 2047;
  const int t = threadIdx.x;
  {
    const float4* xg = (const float4*)(x + ((size_t)bl << 12));
    const float4* ug = (const float4*)u;
#pragma unroll
    for (int i = 0; i < 4; ++i) {
      ((float4*)xs)[t + 256 * i] = xg[t + 256 * i];
      ((float4*)us)[t + 256 * i] = ug[t + 256 * i];
    }
  }
  __syncthreads();
  // tmp[m][d] = sum_n u[n][m] * x[n][d]; each thread a 4x4 tile
  {
    const int m0 = (t >> 4) << 2, d0 = (t & 15) << 2;
    float acc[4][4] = {};
    for (int n = 0; n < 64; ++n) {
      float uv[4], xv[4];
      *(float4*)uv = *(const float4*)&us[n * 64 + m0];
      *(float4*)xv = *(const float4*)&xs[n * 64 + d0];
#pragma unroll
      for (int i = 0; i < 4; ++i)
#pragma unroll
        for (int j = 0; j < 4; ++j) acc[i][j] += uv[i] * xv[j];
    }
#pragma unroll
    for (int i = 0; i < 4; ++i)
#pragma unroll
      for (int j = 0; j < 4; ++j) tmps[(d0 + j) * 64 + m0 + i] = acc[i][j];
  }
  __syncthreads();
  // qkv[m][k] = sum_d tmp[m][d] * v[d][k]; each thread 4m x 12k, then scatter
  {
    const int m0 = (t >> 4) << 2, k0 = (t & 15) * 12;
    float acc[4][12] = {};
    for (int d = 0; d < 64; ++d) {
      float tv[4], vv[12];
      *(float4*)tv = *(const float4*)&tmps[d * 64 + m0];
      const float* vr = v + d * 192 + k0;
      *(float4*)&vv[0] = *(const float4*)&vr[0];
      *(float4*)&vv[4] = *(const float4*)&vr[4];
      *(float4*)&vv[8] = *(const float4*)&vr[8];
#pragma unroll
      for (int i = 0; i < 4; ++i)
#pragma unroll
        for (int j = 0; j < 12; ++j) acc[i][j] += tv[i] * vv[j];
    }
#pragma unroll
    for (int i = 0; i < 4; ++i)
#pragma unroll
      for (int j = 0; j < 12; ++j) {
        const int idx = (m0 + i) * 192 + k0 + j;  // flat (m,k) index
        const int t3 = idx >> 12;                 // q/k/v selector
        const int ch = (idx >> 6) & 63;           // mc*16 + hc
        const int rl = idx & 63;                  // mr*16 + hr
        const int f = ((ch & 15) << 4) | (rl & 15);
        const int h = (b << 4) | (((ch >> 4)) << 2) | (rl >> 4);
        const _Float16 val = (_Float16)acc[i][j];
        const size_t off = (((size_t)h * 2048 + l) << 8) + f;
        if (t3 == 0)
          Q[off] = val;
        else if (t3 == 1)
          K[off] = val;
        else
          V[off] = val;  // coalesced-ish [h][l][f]; transposed later
      }
  }
}

// ---------------- Kernel A2: V [h][l][f] -> Vt [h][f][l] (64x64 LDS tiles) ------
__global__ __launch_bounds__(256) void vtrans_kernel(
    const _Float16* __restrict__ V, _Float16* __restrict__ Vt) {
  __shared__ _Float16 tb[64 * 72];
  const int bid = blockIdx.x;
  const int h = bid >> 7;          // 32 heads
  const int lt = (bid >> 2) & 31;  // 32 l-tiles
  const int ft = bid & 3;          // 4 f-tiles
  const int l0 = lt << 6, f0 = ft << 6;
  const int t = threadIdx.x;
  const int r = t >> 2, s = (t & 3) << 4;
  const _Float16* src = V + (((size_t)h * 2048 + l0 + r) << 8) + f0 + s;
  *(f16x8*)(tb + r * 72 + s) = *(const f16x8*)src;
  *(f16x8*)(tb + r * 72 + s + 8) = *(const f16x8*)(src + 8);
  __syncthreads();
  _Float16 buf[16];
#pragma unroll
  for (int j = 0; j < 16; ++j) buf[j] = tb[(s + j) * 72 + r];
  _Float16* dst = Vt + (((size_t)(h << 8) + f0 + r) << 11) + l0 + s;
  *(f16x8*)dst = *(f16x8*)buf;
  *(f16x8*)(dst + 8) = *(f16x8*)(buf + 8);
}

// ---------------- Kernel B: flash attention, double-buffered pipeline ----------
__global__ __launch_bounds__(256, 2) void attn_kernel(
    const _Float16* __restrict__ Q, const _Float16* __restrict__ K,
    const _Float16* __restrict__ Vt, _Float16* __restrict__ O) {
  __shared__ _Float16 Ks[2][32 * 256];  // mem[row][u] = K[row][u ^ (row&7)] (16B units)
  __shared__ _Float16 Vs[2][256 * 32];  // [feat][key]
  __shared__ _Float16 Ps[4][32 * 32];   // per-wave P transpose buffer [q][key]
  // XCD swizzle: each XCD owns 4 heads x all 16 q-tiles (K/V reuse in its L2)
  const int i = blockIdx.x;
  const int h = (i & 7) * 4 + (i >> 7);
  const int qt = (i >> 3) & 15;
  const int tid = threadIdx.x;
  const int w = tid >> 6, lane = tid & 63;
  const int l15 = lane & 15, quad = lane >> 4;
  const int q0 = qt * 128 + w * 32;  // this wave's 32 queries

  const _Float16* Kt = K + (((size_t)h * 2048) << 8);
  const _Float16* Vtb = Vt + (((size_t)h << 8) << 11);

  // Q fragments, two 16-query halves (A-op: m=l15 -> query, k=quad*8+j -> feat)
  f16x8 qf[2][8];
#pragma unroll
  for (int qh = 0; qh < 2; ++qh) {
    const _Float16* qb = Q + (((size_t)h * 2048 + q0 + qh * 16 + l15) << 8) + quad * 8;
#pragma unroll
    for (int kc = 0; kc < 8; ++kc) qf[qh][kc] = *(const f16x8*)(qb + kc * 32);
  }

  f32x4 oacc[2][16];
#pragma unroll
  for (int qh = 0; qh < 2; ++qh)
#pragma unroll
    for (int ch = 0; ch < 16; ++ch) oacc[qh][ch] = (f32x4){0.f, 0.f, 0.f, 0.f};
  float m2[2][4], ell[2][4];
#pragma unroll
  for (int qh = 0; qh < 2; ++qh)
#pragma unroll
    for (int r = 0; r < 4; ++r) { m2[qh][r] = -1e30f; ell[qh][r] = 0.f; }
  const float SC = 23.083120654223414f;  // 16 * log2(e)

  // stage one 32-key tile (8 x 16B per thread: K0,V0,K1,V1,K2,V2,K3,V3)
  auto stage_tile = [&](int kt, int bb) {
    const int k0 = kt * 32;
#pragma unroll
    for (int o = 0; o < 4; ++o) {
      const int c = tid + o * 256;
      const int row = c >> 5, unit = c & 31;
      stage16(Kt + (((size_t)(k0 + row)) << 8) + ((unit ^ (row & 7)) << 3),
              &Ks[bb][c * 8]);
      const int f = c >> 2, ku = c & 3;
      stage16(Vtb + (((size_t)f) << 11) + k0 + ku * 8, &Vs[bb][c * 8]);
    }
  };

  stage_tile(0, 0);
  for (int kt = 0; kt < 64; ++kt) {
    const int cb = kt & 1;
    if (kt < 63) {
      stage_tile(kt + 1, cb ^ 1);
      asm volatile("s_waitcnt vmcnt(8)" ::: "memory");  // cur tile landed
    } else {
      asm volatile("s_waitcnt vmcnt(0)" ::: "memory");
    }
    __builtin_amdgcn_s_barrier();  // raw: do NOT drain the prefetch
    asm volatile("" ::: "memory");

    // S = Q K^T : two key-halves, two query-halves; K frags shared across qh
    f32x4 c00 = {0.f, 0.f, 0.f, 0.f}, c01 = c00, c10 = c00, c11 = c00;
#pragma unroll
    for (int kc = 0; kc < 8; ++kc) {
      const int u0 = ((kc * 4 + quad) ^ (l15 & 7)) << 3;
      f16x8 kf0 = *(const f16x8*)(&Ks[cb][l15 * 256 + u0]);
      f16x8 kf1 = *(const f16x8*)(&Ks[cb][(16 + l15) * 256 + u0]);
      c00 = __builtin_amdgcn_mfma_f32_16x16x32_f16(qf[0][kc], kf0, c00, 0, 0, 0);
      c01 = __builtin_amdgcn_mfma_f32_16x16x32_f16(qf[0][kc], kf1, c01, 0, 0, 0);
      c10 = __builtin_amdgcn_mfma_f32_16x16x32_f16(qf[1][kc], kf0, c10, 0, 0, 0);
      c11 = __builtin_amdgcn_mfma_f32_16x16x32_f16(qf[1][kc], kf1, c11, 0, 0, 0);
    }

    // online softmax (lane-partial ell; reduce only max per iter)
    float alpha[2][4];
    bool upd = false;
    _Float16* pb = Ps[w];
#pragma unroll
    for (int qh = 0; qh < 2; ++qh) {
#pragma unroll
      for (int r = 0; r < 4; ++r) {
        const float s0 = (qh ? c10[r] : c00[r]) * SC;
        const float s1 = (qh ? c11[r] : c01[r]) * SC;
        float mx = fmaxf(s0, s1);
        mx = fmaxf(mx, __shfl_xor(mx, 1));
        mx = fmaxf(mx, __shfl_xor(mx, 2));
        mx = fmaxf(mx, __shfl_xor(mx, 4));
        mx = fmaxf(mx, __shfl_xor(mx, 8));
        const float mo = m2[qh][r];
        const float mn = fmaxf(mo, mx);
        m2[qh][r] = mn;
        upd |= (mx > mo);
        const float a = exp2f(mo - mn);
        alpha[qh][r] = a;
        const float p0 = exp2f(s0 - mn), p1 = exp2f(s1 - mn);
        ell[qh][r] = ell[qh][r] * a + (p0 + p1);
        const int rowq = (qh * 16 + quad * 4 + r) * 32;
        pb[rowq + l15] = (_Float16)p0;
        pb[rowq + 16 + l15] = (_Float16)p1;
      }
    }
    if (__any(upd)) {
#pragma unroll
      for (int qh = 0; qh < 2; ++qh) {
        const f32x4 av = {alpha[qh][0], alpha[qh][1], alpha[qh][2], alpha[qh][3]};
#pragma unroll
        for (int ch = 0; ch < 16; ++ch) oacc[qh][ch] *= av;
      }
    }
    asm volatile("s_waitcnt lgkmcnt(0)" ::: "memory");
    f16x8 pf0 = *(const f16x8*)(pb + l15 * 32 + quad * 8);
    f16x8 pf1 = *(const f16x8*)(pb + (16 + l15) * 32 + quad * 8);
    // O += P V  (V frags shared across the two query-halves)
#pragma unroll
    for (int ch = 0; ch < 16; ++ch) {
      f16x8 vf = *(const f16x8*)(&Vs[cb][(ch * 16 + l15) * 32 + quad * 8]);
      oacc[0][ch] = __builtin_amdgcn_mfma_f32_16x16x32_f16(pf0, vf, oacc[0][ch], 0, 0, 0);
      oacc[1][ch] = __builtin_amdgcn_mfma_f32_16x16x32_f16(pf1, vf, oacc[1][ch], 0, 0, 0);
    }
    asm volatile("" ::: "memory");
    __builtin_amdgcn_s_barrier();  // all waves done with cb before restage
  }

  // epilogue: reduce lane-partial ell across the 16-lane row groups, write O
#pragma unroll
  for (int qh = 0; qh < 2; ++qh) {
    float inv[4];
#pragma unroll
    for (int r = 0; r < 4; ++r) {
      float e = ell[qh][r];
      e += __shfl_xor(e, 1);
      e += __shfl_xor(e, 2);
      e += __shfl_xor(e, 4);
      e += __shfl_xor(e, 8);
      inv[r] = 1.f / e;
    }
    _Float16* ob = O + (((size_t)h * 2048 + q0 + qh * 16 + quad * 4) << 8) + l15;
#pragma unroll
    for (int r = 0; r < 4; ++r)
#pragma unroll
      for (int ch = 0; ch < 16; ++ch)
        ob[((size_t)r << 8) + ch * 16] = (_Float16)(oacc[qh][ch][r] * inv[r]);
  }
}

// ---------------- Kernel C: gather heads + output bilinear projection -----------
__global__ __launch_bounds__(256) void proj_kernel(
    const _Float16* __restrict__ O, const float* __restrict__ pu,
    const float* __restrict__ pv, float* __restrict__ out) {
  __shared__ float os[4096];    // [n=mc*16+hc][d=mr*16+hr]
  __shared__ float pus[4096];   // proj_u [n][m]
  __shared__ float tmps[4096];  // [d][m]
  const int bl = blockIdx.x;
  const int b = bl >> 11, l = bl & 2047;
  const int t = threadIdx.x;
#pragma unroll
  for (int i = 0; i < 4; ++i)
    ((float4*)pus)[t + 256 * i] = ((const float4*)pu)[t + 256 * i];
  {  // gather this (b,l)'s 64x64 attention output from the 16 heads
    const int hh = t >> 4, hc = t & 15;
    const int mc = hh >> 2, mr = hh & 3;
    const int hg = (b << 4) | hh;
    const _Float16* src = O + (((size_t)hg * 2048 + l) << 8) + hc * 16;
    float* dst = os + (mc * 16 + hc) * 64 + mr * 16;
    f16x8 v0 = *(const f16x8*)(src);
    f16x8 v1 = *(const f16x8*)(src + 8);
#pragma unroll
    for (int j = 0; j < 8; ++j) {
      dst[j] = (float)v0[j];
      dst[8 + j] = (float)v1[j];
    }
  }
  __syncthreads();
  {  // tmp[m][d] = sum_n pu[n][m] * os[n][d]
    const int m0 = (t >> 4) << 2, d0 = (t & 15) << 2;
    float acc[4][4] = {};
    for (int n = 0; n < 64; ++n) {
      float uv[4], xv[4];
      *(float4*)uv = *(const float4*)&pus[n * 64 + m0];
      *(float4*)xv = *(const float4*)&os[n * 64 + d0];
#pragma unroll
      for (int i = 0; i < 4; ++i)
#pragma unroll
        for (int j = 0; j < 4; ++j) acc[i][j] += uv[i] * xv[j];
    }
#pragma unroll
    for (int i = 0; i < 4; ++i)
#pragma unroll
      for (int j = 0; j < 4; ++j) tmps[(d0 + j) * 64 + m0 + i] = acc[i][j];
  }
  __syncthreads();
  {  // out[m][k] = sum_d tmp[m][d] * pv[d][k]
    const int m0 = (t >> 4) << 2, k0 = (t & 15) << 2;
    float acc[4][4] = {};
    for (int d = 0; d < 64; ++d) {
      float tv[4], vv[4];
      *(float4*)tv = *(const float4*)&tmps[d * 64 + m0];
      *(float4*)vv = *(const float4*)&pv[d * 64 + k0];
#pragma unroll
      for (int i = 0; i < 4; ++i)
#pragma unroll
        for (int j = 0; j < 4; ++j) acc[i][j] += tv[i] * vv[j];
    }
    float* og = out + ((size_t)bl << 12);
#pragma unroll
    for (int i = 0; i < 4; ++i) {
      float4 r;
      r.x = acc[i][0]; r.y = acc[i][1]; r.z = acc[i][2]; r.w = acc[i][3];
      *(float4*)&og[(m0 + i) * 64 + k0] = r;
    }
  }
}

extern "C" void kernel_launch(void* const* d_in, const int* in_sizes, int n_in,
                              void* d_out, int out_size, void* d_ws, size_t ws_size,
                              hipStream_t stream) {
  (void)in_sizes; (void)n_in; (void)out_size; (void)ws_size;
  const float* x = (const float*)d_in[0];
  const float* u = (const float*)d_in[1];
  const float* v = (const float*)d_in[2];
  const float* pu = (const float*)d_in[3];
  const float* pv = (const float*)d_in[4];
  const size_t SEG = (size_t)32 * 2048 * 256;  // 16.7M f16 elements
  _Float16* Q = (_Float16*)d_ws;
  _Float16* K = Q + SEG;
  _Float16* Vt = K + SEG;
  _Float16* O = Vt + SEG;   // also serves as V staging (consumed before O writes)
  _Float16* V = O;
  qkv_kernel<<<4096, 256, 0, stream>>>(x, u, v, Q, K, V);
  vtrans_kernel<<<4096, 256, 0, stream>>>(V, Vt);
  attn_kernel<<<512, 256, 0, stream>>>(Q, K, Vt, O);
  proj_kernel<<<4096, 256, 0, stream>>>(O, pu, pv, (float*)d_out);
}

// Round 4
// 547.243 us; speedup vs baseline: 1.5024x; 1.2687x over previous
//
#include <hip/hip_runtime.h>
#include <hip/hip_fp16.h>

typedef _Float16 f16x8 __attribute__((ext_vector_type(8)));
typedef _Float16 f16x4 __attribute__((ext_vector_type(4)));
typedef float f32x4 __attribute__((ext_vector_type(4)));

// Problem: B=2, L=2048, C=R=64. heads h = b*16 + mc*4 + mr (32 total),
// feature f = hc*16 + hr (256). Workspace (f16):
//   Q [32][2048][256], K [32][2048][256], Vt [32][256][2048], O/V [32][2048][256]

__device__ __forceinline__ void stage16(const _Float16* g, _Float16* l) {
  __builtin_amdgcn_global_load_lds(
      (const __attribute__((address_space(1))) void*)g,
      (__attribute__((address_space(3))) void*)l, 16, 0, 0);
}

__device__ __forceinline__ unsigned int pk2(float a, float b) {
  union { _Float16 h[2]; unsigned int u; } x;
  x.h[0] = (_Float16)a; x.h[1] = (_Float16)b;
  return x.u;
}

// ---------------- Kernel A: QKV bilinear projection, coalesced f16 stores -------
__global__ __launch_bounds__(256) void qkv_kernel(
    const float* __restrict__ x, const float* __restrict__ u,
    const float* __restrict__ v, _Float16* __restrict__ Q,
    _Float16* __restrict__ K, _Float16* __restrict__ V) {
  __shared__ float smem[12288];  // [0,4K):xs/vchunk  [4K,8K):us  [8K,12K):tmps
  float* xs = smem;
  float* us = smem + 4096;
  float* tmps = smem + 8192;
  float* vch = smem;                 // v chunk [16][192], reuses xs after gemm1
  _Float16* qk16 = (_Float16*)smem;  // f16 qkv [64][192] = 24 KB, after gemm2
  const int bl = blockIdx.x;
  const int b = bl >> 11, l = bl & 2047;
  const int t = threadIdx.x;
  {
    const float4* xg = (const float4*)(x + ((size_t)bl << 12));
    const float4* ug = (const float4*)u;
#pragma unroll
    for (int i = 0; i < 4; ++i) {
      ((float4*)xs)[t + 256 * i] = xg[t + 256 * i];
      ((float4*)us)[t + 256 * i] = ug[t + 256 * i];
    }
  }
  __syncthreads();
  // gemm1: tmp[m][d] = sum_n u[n][m] x[n][d]; thread 4x4 tile -> tmps[d][m]
  {
    const int m0 = (t >> 4) << 2, d0 = (t & 15) << 2;
    float acc[4][4] = {};
    for (int n = 0; n < 64; ++n) {
      float uv[4], xv[4];
      *(float4*)uv = *(const float4*)&us[n * 64 + m0];
      *(float4*)xv = *(const float4*)&xs[n * 64 + d0];
#pragma unroll
      for (int i = 0; i < 4; ++i)
#pragma unroll
        for (int j = 0; j < 4; ++j) acc[i][j] += uv[i] * xv[j];
    }
#pragma unroll
    for (int i = 0; i < 4; ++i)
#pragma unroll
      for (int j = 0; j < 4; ++j) tmps[(d0 + j) * 64 + m0 + i] = acc[i][j];
  }
  __syncthreads();
  // gemm2: qkv[m][k] = sum_d tmp[m][d] v[d][k]; v staged in 4 LDS chunks
  const int m0 = (t >> 4) << 2, k0 = (t & 15) * 12;
  float acc[4][12] = {};
  for (int c = 0; c < 4; ++c) {
    const float4* vg = (const float4*)(v + c * 16 * 192);
#pragma unroll
    for (int s = 0; s < 3; ++s) ((float4*)vch)[t + 256 * s] = vg[t + 256 * s];
    __syncthreads();
    for (int dd = 0; dd < 16; ++dd) {
      const int d = c * 16 + dd;
      float tv[4], vv[12];
      *(float4*)tv = *(const float4*)&tmps[d * 64 + m0];
      const float* vr = vch + dd * 192 + k0;
      *(float4*)&vv[0] = *(const float4*)&vr[0];
      *(float4*)&vv[4] = *(const float4*)&vr[4];
      *(float4*)&vv[8] = *(const float4*)&vr[8];
#pragma unroll
      for (int i = 0; i < 4; ++i)
#pragma unroll
        for (int j = 0; j < 12; ++j) acc[i][j] += tv[i] * vv[j];
    }
    __syncthreads();
  }
  // write f16 qkv into LDS (overwrites xs/us region only)
#pragma unroll
  for (int i = 0; i < 4; ++i) {
    f16x4 h0, h1, h2;
#pragma unroll
    for (int j = 0; j < 4; ++j) {
      h0[j] = (_Float16)acc[i][j];
      h1[j] = (_Float16)acc[i][4 + j];
      h2[j] = (_Float16)acc[i][8 + j];
    }
    _Float16* dst = qk16 + (m0 + i) * 192 + k0;
    *(f16x4*)dst = h0;
    *(f16x4*)(dst + 4) = h1;
    *(f16x4*)(dst + 8) = h2;
  }
  __syncthreads();
  // gather + coalesced 32B stores: run rho = m*12 + k64*4 + mr -> 16 consecutive f
#pragma unroll
  for (int s = 0; s < 3; ++s) {
    const int rho = t + 256 * s;
    const int m = rho / 12, rem = rho - m * 12;
    const int k64 = rem >> 2, mr = rem & 3;
    const int chf = 3 * m + k64;          // t3*64 + ch
    const int t3 = chf >> 6, ch = chf & 63;
    const int f0 = (ch & 15) << 4;
    const int h = (b << 4) | ((ch >> 4) << 2) | mr;
    const _Float16* src = qk16 + m * 192 + k64 * 64 + mr * 16;
    f16x8 a0 = *(const f16x8*)src;
    f16x8 a1 = *(const f16x8*)(src + 8);
    _Float16* base = (t3 == 0) ? Q : (t3 == 1) ? K : V;
    _Float16* dst = base + (((size_t)h * 2048 + l) << 8) + f0;
    *(f16x8*)dst = a0;
    *(f16x8*)(dst + 8) = a1;
  }
}

// ---------------- Kernel A2: V [h][l][f] -> Vt [h][f][l] (64x64 LDS tiles) ------
__global__ __launch_bounds__(256) void vtrans_kernel(
    const _Float16* __restrict__ V, _Float16* __restrict__ Vt) {
  __shared__ _Float16 tb[64 * 72];
  const int bid = blockIdx.x;
  const int h = bid >> 7;
  const int lt = (bid >> 2) & 31;
  const int ft = bid & 3;
  const int l0 = lt << 6, f0 = ft << 6;
  const int t = threadIdx.x;
  const int r = t >> 2, s = (t & 3) << 4;
  const _Float16* src = V + (((size_t)h * 2048 + l0 + r) << 8) + f0 + s;
  *(f16x8*)(tb + r * 72 + s) = *(const f16x8*)src;
  *(f16x8*)(tb + r * 72 + s + 8) = *(const f16x8*)(src + 8);
  __syncthreads();
  _Float16 buf[16];
#pragma unroll
  for (int j = 0; j < 16; ++j) buf[j] = tb[(s + j) * 72 + r];
  _Float16* dst = Vt + (((size_t)(h << 8) + f0 + r) << 11) + l0 + s;
  *(f16x8*)dst = *(f16x8*)buf;
  *(f16x8*)(dst + 8) = *(f16x8*)(buf + 8);
}

// ---------------- Kernel B: flash attention, S^T dataflow, MFMA 16x16x32 --------
__global__ __launch_bounds__(256, 2) void attn_kernel(
    const _Float16* __restrict__ Q, const _Float16* __restrict__ K,
    const _Float16* __restrict__ Vt, _Float16* __restrict__ O) {
  __shared__ _Float16 Ks[2][32 * 256];     // swizzled: mem[row][u]=K[row][u^(row&7)]
  __shared__ _Float16 Vs[2][256 * 32];     // [feat][key]
  __shared__ unsigned int Ps[4 * 32 * 18]; // per-wave P^T rows, 18-dword stride
  const int i = blockIdx.x;
  const int h = (i & 7) * 4 + (i >> 7);    // XCD-aware: 4 heads per XCD
  const int qt = (i >> 3) & 15;
  const int tid = threadIdx.x;
  const int w = tid >> 6, lane = tid & 63;
  const int l15 = lane & 15, quad = lane >> 4;
  const int q0 = qt * 128 + w * 32;

  const _Float16* Kt = K + (((size_t)h * 2048) << 8);
  const _Float16* Vtb = Vt + (((size_t)h << 8) << 11);

  // Q fragments as B-operand (n=query=l15, k=feat=kc*32+quad*8+j)
  f16x8 qf[2][8];
#pragma unroll
  for (int qh = 0; qh < 2; ++qh) {
    const _Float16* qb = Q + (((size_t)h * 2048 + q0 + qh * 16 + l15) << 8) + quad * 8;
#pragma unroll
    for (int kc = 0; kc < 8; ++kc) qf[qh][kc] = *(const f16x8*)(qb + kc * 32);
  }

  // O^T accumulators: oacc[qh][fb][r] = O^T[feat=fb*16+quad*4+r][query=qh*16+l15]
  f32x4 oacc[2][16];
#pragma unroll
  for (int qh = 0; qh < 2; ++qh)
#pragma unroll
    for (int fb = 0; fb < 16; ++fb) oacc[qh][fb] = (f32x4){0.f, 0.f, 0.f, 0.f};
  float m2[2] = {-1e30f, -1e30f};  // running max per query (base-2 units)
  float ell[2] = {0.f, 0.f};      // lane-partial (this quad's keys)
  const float SC = 23.083120654223414f;  // 16 * log2(e)

  auto stage_tile = [&](int kt, int bb) {
    const int k0 = kt * 32;
#pragma unroll
    for (int o = 0; o < 4; ++o) {
      const int c = tid + o * 256;
      const int row = c >> 5, unit = c & 31;
      stage16(Kt + (((size_t)(k0 + row)) << 8) + ((unit ^ (row & 7)) << 3),
              &Ks[bb][c * 8]);
      const int f = c >> 2, ku = c & 3;
      stage16(Vtb + (((size_t)f) << 11) + k0 + ku * 8, &Vs[bb][c * 8]);
    }
  };

  unsigned int* pw = Ps + w * 32 * 18;
  stage_tile(0, 0);
  for (int kt = 0; kt < 64; ++kt) {
    const int cb = kt & 1;
    if (kt < 63) {
      stage_tile(kt + 1, cb ^ 1);
      asm volatile("s_waitcnt vmcnt(8)" ::: "memory");
    } else {
      asm volatile("s_waitcnt vmcnt(0)" ::: "memory");
    }
    __builtin_amdgcn_s_barrier();
    asm volatile("" ::: "memory");

    // S^T = K Q^T : c[kh][qh]; D[m=key=quad*4+r][n=query=l15]
    f32x4 c00 = {0.f, 0.f, 0.f, 0.f}, c01 = c00, c10 = c00, c11 = c00;
#pragma unroll
    for (int kc = 0; kc < 8; ++kc) {
      const int u0 = ((kc * 4 + quad) ^ (l15 & 7)) << 3;
      f16x8 kf0 = *(const f16x8*)(&Ks[cb][l15 * 256 + u0]);
      f16x8 kf1 = *(const f16x8*)(&Ks[cb][(16 + l15) * 256 + u0]);
      c00 = __builtin_amdgcn_mfma_f32_16x16x32_f16(kf0, qf[0][kc], c00, 0, 0, 0);
      c01 = __builtin_amdgcn_mfma_f32_16x16x32_f16(kf0, qf[1][kc], c01, 0, 0, 0);
      c10 = __builtin_amdgcn_mfma_f32_16x16x32_f16(kf1, qf[0][kc], c10, 0, 0, 0);
      c11 = __builtin_amdgcn_mfma_f32_16x16x32_f16(kf1, qf[1][kc], c11, 0, 0, 0);
    }

    // online softmax: in-lane 8-max + xor16/xor32; lane-partial ell
    float alpha[2];
    bool upd = false;
#pragma unroll
    for (int qh = 0; qh < 2; ++qh) {
      const f32x4 ck0 = qh ? c01 : c00;
      const f32x4 ck1 = qh ? c11 : c10;
      float s0[4], s1[4];
#pragma unroll
      for (int r = 0; r < 4; ++r) { s0[r] = ck0[r] * SC; s1[r] = ck1[r] * SC; }
      float mx = fmaxf(fmaxf(fmaxf(s0[0], s0[1]), fmaxf(s0[2], s0[3])),
                       fmaxf(fmaxf(s1[0], s1[1]), fmaxf(s1[2], s1[3])));
      mx = fmaxf(mx, __shfl_xor(mx, 16));
      mx = fmaxf(mx, __shfl_xor(mx, 32));
      const float mo = m2[qh];
      const float mn = fmaxf(mo, mx);
      m2[qh] = mn;
      upd |= (mx > mo);
      const float a = exp2f(mo - mn);
      alpha[qh] = a;
      float p0[4], p1[4];
#pragma unroll
      for (int r = 0; r < 4; ++r) { p0[r] = exp2f(s0[r] - mn); p1[r] = exp2f(s1[r] - mn); }
      ell[qh] = ell[qh] * a + ((p0[0] + p0[1]) + (p0[2] + p0[3])) +
                ((p1[0] + p1[1]) + (p1[2] + p1[3]));
      // P^T row (query) stores: dword column = key-pair index
      unsigned int* row = pw + (qh * 16 + l15) * 18;
      row[quad * 2 + 0] = pk2(p0[0], p0[1]);
      row[quad * 2 + 1] = pk2(p0[2], p0[3]);
      row[8 + quad * 2 + 0] = pk2(p1[0], p1[1]);
      row[8 + quad * 2 + 1] = pk2(p1[2], p1[3]);
    }
    if (__any(upd)) {
#pragma unroll
      for (int qh = 0; qh < 2; ++qh)
#pragma unroll
        for (int fb = 0; fb < 16; ++fb) oacc[qh][fb] *= alpha[qh];
    }
    // read P^T B-frags (keys quad*8..quad*8+7 for query l15)
    f16x8 pf[2];
#pragma unroll
    for (int qh = 0; qh < 2; ++qh) {
      const _Float16* pr = (const _Float16*)(pw + (qh * 16 + l15) * 18);
      union { f16x8 v; f16x4 h[2]; } tmp;
      tmp.h[0] = *(const f16x4*)(pr + quad * 8);
      tmp.h[1] = *(const f16x4*)(pr + quad * 8 + 4);
      pf[qh] = tmp.v;
    }
    // O^T += V^T P^T (vf shared across qh)
#pragma unroll
    for (int fb = 0; fb < 16; ++fb) {
      f16x8 vf = *(const f16x8*)(&Vs[cb][(fb * 16 + l15) * 32 + quad * 8]);
      oacc[0][fb] = __builtin_amdgcn_mfma_f32_16x16x32_f16(vf, pf[0], oacc[0][fb], 0, 0, 0);
      oacc[1][fb] = __builtin_amdgcn_mfma_f32_16x16x32_f16(vf, pf[1], oacc[1][fb], 0, 0, 0);
    }
    asm volatile("" ::: "memory");
    __builtin_amdgcn_s_barrier();
  }

  // epilogue: reduce lane-partial ell over quads, write O[h][query][feat]
#pragma unroll
  for (int qh = 0; qh < 2; ++qh) {
    float e = ell[qh];
    e += __shfl_xor(e, 16);
    e += __shfl_xor(e, 32);
    const float inv = 1.f / e;
    _Float16* ob = O + (((size_t)h * 2048 + q0 + qh * 16 + l15) << 8) + quad * 4;
#pragma unroll
    for (int fb = 0; fb < 16; ++fb) {
      f16x4 ov;
#pragma unroll
      for (int r = 0; r < 4; ++r) ov[r] = (_Float16)(oacc[qh][fb][r] * inv);
      *(f16x4*)(ob + fb * 16) = ov;
    }
  }
}

// ---------------- Kernel C: gather heads + output bilinear projection -----------
__global__ __launch_bounds__(256) void proj_kernel(
    const _Float16* __restrict__ O, const float* __restrict__ pu,
    const float* __restrict__ pv, float* __restrict__ out) {
  __shared__ float os[4096];    // [n][d] gather; later reused for pv
  __shared__ float pus[4096];   // proj_u [n][m]
  __shared__ float tmps[4096];  // [d][m]
  const int bl = blockIdx.x;
  const int b = bl >> 11, l = bl & 2047;
  const int t = threadIdx.x;
#pragma unroll
  for (int i = 0; i < 4; ++i)
    ((float4*)pus)[t + 256 * i] = ((const float4*)pu)[t + 256 * i];
  {  // gather this (b,l)'s 64x64 attention output from the 16 heads
    const int hh = t >> 4, hc = t & 15;
    const int mc = hh >> 2, mr = hh & 3;
    const int hg = (b << 4) | hh;
    const _Float16* src = O + (((size_t)hg * 2048 + l) << 8) + hc * 16;
    float* dst = os + (mc * 16 + hc) * 64 + mr * 16;
    f16x8 v0 = *(const f16x8*)(src);
    f16x8 v1 = *(const f16x8*)(src + 8);
#pragma unroll
    for (int j = 0; j < 8; ++j) {
      dst[j] = (float)v0[j];
      dst[8 + j] = (float)v1[j];
    }
  }
  __syncthreads();
  {  // tmp[m][d] = sum_n pu[n][m] * os[n][d]
    const int m0 = (t >> 4) << 2, d0 = (t & 15) << 2;
    float acc[4][4] = {};
    for (int n = 0; n < 64; ++n) {
      float uv[4], xv[4];
      *(float4*)uv = *(const float4*)&pus[n * 64 + m0];
      *(float4*)xv = *(const float4*)&os[n * 64 + d0];
#pragma unroll
      for (int i = 0; i < 4; ++i)
#pragma unroll
        for (int j = 0; j < 4; ++j) acc[i][j] += uv[i] * xv[j];
    }
    __syncthreads();  // os fully consumed before overwrite
#pragma unroll
    for (int i = 0; i < 4; ++i)
#pragma unroll
      for (int j = 0; j < 4; ++j) tmps[(d0 + j) * 64 + m0 + i] = acc[i][j];
  }
  // stage pv into os region
#pragma unroll
  for (int i = 0; i < 4; ++i)
    ((float4*)os)[t + 256 * i] = ((const float4*)pv)[t + 256 * i];
  __syncthreads();
  {  // out[m][k] = sum_d tmp[m][d] * pv[d][k]
    const int m0 = (t >> 4) << 2, k0 = (t & 15) << 2;
    float acc[4][4] = {};
    for (int d = 0; d < 64; ++d) {
      float tv[4], vv[4];
      *(float4*)tv = *(const float4*)&tmps[d * 64 + m0];
      *(float4*)vv = *(const float4*)&os[d * 64 + k0];
#pragma unroll
      for (int i = 0; i < 4; ++i)
#pragma unroll
        for (int j = 0; j < 4; ++j) acc[i][j] += tv[i] * vv[j];
    }
    float* og = out + ((size_t)bl << 12);
#pragma unroll
    for (int i = 0; i < 4; ++i) {
      float4 r;
      r.x = acc[i][0]; r.y = acc[i][1]; r.z = acc[i][2]; r.w = acc[i][3];
      *(float4*)&og[(m0 + i) * 64 + k0] = r;
    }
  }
}

extern "C" void kernel_launch(void* const* d_in, const int* in_sizes, int n_in,
                              void* d_out, int out_size, void* d_ws, size_t ws_size,
                              hipStream_t stream) {
  (void)in_sizes; (void)n_in; (void)out_size; (void)ws_size;
  const float* x = (const float*)d_in[0];
  const float* u = (const float*)d_in[1];
  const float* v = (const float*)d_in[2];
  const float* pu = (const float*)d_in[3];
  const float* pv = (const float*)d_in[4];
  const size_t SEG = (size_t)32 * 2048 * 256;  // 16.7M f16 elements
  _Float16* Q = (_Float16*)d_ws;
  _Float16* K = Q + SEG;
  _Float16* Vt = K + SEG;
  _Float16* O = Vt + SEG;  // also V staging (consumed by vtrans before O writes)
  _Float16* V = O;
  qkv_kernel<<<4096, 256, 0, stream>>>(x, u, v, Q, K, V);
  vtrans_kernel<<<4096, 256, 0, stream>>>(V, Vt);
  attn_kernel<<<512, 256, 0, stream>>>(Q, K, Vt, O);
  proj_kernel<<<4096, 256, 0, stream>>>(O, pu, pv, (float*)d_out);
}